// Round 5
// baseline (1801.390 us; speedup 1.0000x reference)
//
#include <hip/hip_runtime.h>

// ---------------------------------------------------------------------------
// Elman RNN forward: out = mean_t( h_t ) @ Wfc + bfc,
//   h_t = relu( emb[x[:,t]] @ Wxh + bxh + h_{t-1} @ Whh + bhh )
// V=100000 E=512 H=512 B=256 S=200
//
// Round-5: identical to round 3/4 (never ran — GPU acquisition timeouts).
// Round-3 fix recap: tile swizzle was XOR of a 2-bit slot with a 3-bit row
// field -> row overflow + OOB weight reads in k0 (k index up to 543>511) ->
// garbage weights -> exponential recurrence blowup (3e34). All 4-slot-per-row
// tiles now use slot ^ ((row>>2)&3) (2-bit, in-bounds, <=2-way banks per
// 16-lane phase). h-buffer keeps 6-bit-slot ^ (row&7) (bijective, no OOB).
//
// ws layout: [0,512K) wxhT | [512K,1M) whhT | [1M,1.25M) hstate bf16
//   | [1.25M,1.75M) poolws f32 | [2M, 2M+tc*256K) P chunk (tc | 200)
// ---------------------------------------------------------------------------

#define DEVI __device__ __forceinline__

using short8 = __attribute__((ext_vector_type(8))) short;   // 8 bf16 = 4 VGPR
using f32x4  = __attribute__((ext_vector_type(4))) float;
using u16 = unsigned short;
using u32 = unsigned int;

DEVI u16 f2bf(float x) {                       // RNE float -> bf16
  u32 u = __float_as_uint(x);
  return (u16)((u + 0x7fffu + ((u >> 16) & 1u)) >> 16);
}
DEVI float bf2f(u16 v) { return __uint_as_float(((u32)v) << 16); }

DEVI void glds16(const void* g, void* l) {     // 16B-wide global -> LDS DMA
  __builtin_amdgcn_global_load_lds(
      (const __attribute__((address_space(1))) u32*)g,
      (__attribute__((address_space(3))) u32*)l, 16, 0, 0);
}

// ---------------------------------------------------------------------------
// K0: pack weights into bf16 B-fragment tiles.
//  wxhT: 64 tiles (nt 0..3, kt 0..15), tile = [128 n][32 k], 8KB
//  whhT: 16 tiles (kt 0..15),          tile = [512 n][32 k], 32KB
//  phys slot k8s of row n holds logical k-group k8 = k8s ^ ((n>>2)&3)
// ---------------------------------------------------------------------------
__global__ __launch_bounds__(256) void k0_pack(const float* __restrict__ Wxh,
                                               const float* __restrict__ Whh,
                                               u16* __restrict__ wxhT,
                                               u16* __restrict__ whhT) {
  int id = blockIdx.x * 256 + threadIdx.x;     // 65536 16B-slots total
  if (id < 32768) {                            // Wxh: 64 tiles [128n][32k]
    int tile = id >> 9;
    int s    = id & 511;
    int nt = tile >> 4, kt = tile & 15;
    int n = s >> 2, k8s = s & 3;
    int k8 = k8s ^ ((n >> 2) & 3);             // 2-bit swizzle, in-bounds
    int k0 = kt * 32 + k8 * 8;
    int col = nt * 128 + n;
    u16* dst = wxhT + (size_t)tile * 4096 + n * 32 + k8s * 8;
#pragma unroll
    for (int j = 0; j < 8; j++) dst[j] = f2bf(Wxh[(size_t)(k0 + j) * 512 + col]);
  } else {                                     // Whh: 16 tiles [512n][32k]
    int s2 = id - 32768;
    int kt = s2 >> 11;
    int s  = s2 & 2047;
    int n = s >> 2, k8s = s & 3;
    int k8 = k8s ^ ((n >> 2) & 3);
    int k0 = kt * 32 + k8 * 8;
    u16* dst = whhT + (size_t)kt * 16384 + n * 32 + k8s * 8;
#pragma unroll
    for (int j = 0; j < 8; j++) dst[j] = f2bf(Whh[(size_t)(k0 + j) * 512 + n]);
  }
}

// ---------------------------------------------------------------------------
// K1: P[tl*256+b, :] = emb[x[b, t0+tl]] @ Wxh + bxh + bhh  for tl in [0,tc).
// Grid (2*tc, 4) x 256 thr; 128x128 tile, BK=32, 4 waves (64x64 quadrants).
// ---------------------------------------------------------------------------
__global__ __launch_bounds__(256) void k1_proj(const int* __restrict__ x,
                                               const float* __restrict__ emb,
                                               const u16* __restrict__ wxhT,
                                               const float* __restrict__ bxh,
                                               const float* __restrict__ bhh,
                                               u16* __restrict__ P, int t0) {
  __shared__ __align__(16) char Ablk[8192];    // [128 m][32 k] bf16 swizzled
  __shared__ __align__(16) char Bblk[8192];    // [128 n][32 k] bf16 swizzled

  const int tid = threadIdx.x;
  const int w = tid >> 6, l = tid & 63;
  const int mt = blockIdx.x, nt = blockIdx.y;
  const int mq = (w >> 1) * 64, nq = (w & 1) * 64;
  const int lr = l & 15, k8 = l >> 4;

  const int ar = tid >> 1, ac = (tid & 1) * 16;
  const int m = mt * 128 + ar;                 // local row: tl = m>>8, b = m&255
  unsigned xr = (unsigned)x[(m & 255) * 200 + (t0 + (m >> 8))];
  if (xr >= 100000u) xr = 0;                   // defensive clamp
  const float* arow = emb + (size_t)xr * 512;

  f32x4 af[4];
#pragma unroll
  for (int q = 0; q < 4; q++) af[q] = *(const f32x4*)(arow + ac + q * 4);

  auto storeA = [&]() {
    short8 s0, s1;
#pragma unroll
    for (int j = 0; j < 4; j++) {
      s0[j]     = (short)f2bf(af[0][j]);
      s0[4 + j] = (short)f2bf(af[1][j]);
      s1[j]     = (short)f2bf(af[2][j]);
      s1[4 + j] = (short)f2bf(af[3][j]);
    }
    int hi = ac >> 3;                          // logical slot 0 or 2
    int sw = (ar >> 2) & 3;
    *(short8*)(Ablk + ar * 64 + (((hi)     ^ sw) << 4)) = s0;
    *(short8*)(Ablk + ar * 64 + (((hi + 1) ^ sw) << 4)) = s1;
  };
  auto stageB = [&](int kt) {
    const char* src = (const char*)wxhT + (size_t)(nt * 16 + kt) * 8192;
#pragma unroll
    for (int r = 0; r < 2; r++) {
      int off = r * 4096 + w * 1024;
      glds16(src + off + l * 16, Bblk + off);
    }
  };

  f32x4 acc[4][4];
  f32x4 z = {0.f, 0.f, 0.f, 0.f};
#pragma unroll
  for (int s = 0; s < 4; s++)
#pragma unroll
    for (int u = 0; u < 4; u++) acc[s][u] = z;

  storeA();
  stageB(0);

  for (int kt = 0; kt < 16; kt++) {
    __syncthreads();                           // staged tile visible
    if (kt < 15) {
#pragma unroll
      for (int q = 0; q < 4; q++)
        af[q] = *(const f32x4*)(arow + (kt + 1) * 32 + ac + q * 4);
    }
    short8 a[4], b[4];
#pragma unroll
    for (int s = 0; s < 4; s++) {
      int row = mq + s * 16 + lr;
      a[s] = *(const short8*)(Ablk + row * 64 + ((k8 ^ ((row >> 2) & 3)) << 4));
    }
#pragma unroll
    for (int u = 0; u < 4; u++) {
      int n = nq + u * 16 + lr;
      b[u] = *(const short8*)(Bblk + n * 64 + ((k8 ^ ((n >> 2) & 3)) << 4));
    }
#pragma unroll
    for (int s = 0; s < 4; s++)
#pragma unroll
      for (int u = 0; u < 4; u++)
        acc[s][u] = __builtin_amdgcn_mfma_f32_16x16x32_bf16(a[s], b[u], acc[s][u], 0, 0, 0);
    __syncthreads();                           // reads done, buffers free
    if (kt < 15) { storeA(); stageB(kt + 1); }
  }

  float bsum[4];
#pragma unroll
  for (int u = 0; u < 4; u++) {
    int n = nt * 128 + nq + u * 16 + lr;
    bsum[u] = bxh[n] + bhh[n];
  }
#pragma unroll
  for (int s = 0; s < 4; s++)
#pragma unroll
    for (int u = 0; u < 4; u++)
#pragma unroll
      for (int i = 0; i < 4; i++) {
        int mm = mt * 128 + mq + s * 16 + k8 * 4 + i;   // C/D: row=(l>>4)*4+i
        int c  = nt * 128 + nq + u * 16 + lr;           //      col=l&15
        P[(size_t)mm * 512 + c] = f2bf(acc[s][u][i] + bsum[u]);
      }
}

// ---------------------------------------------------------------------------
// K2: tlen recurrence steps. 16 WGs x 512 thr (8 waves); wave w owns h-cols
// [64w,64w+64). Whh K-tiles 0..9 VGPR-resident, 10..15 streamed in pairs
// (double-buffered). h in LDS bf16 [16 rows][512 cols], 6-bit slot ^ (row&7).
// Chunk state (h, pool) carried through ws when !first / !last.
// ---------------------------------------------------------------------------
#define BRES 10
#define K2_LDS (16384 + 2 * 65536)             // 144 KB

__global__ __launch_bounds__(512, 2) void k2_rnn(const u16* __restrict__ whhT,
                                                 const u16* __restrict__ P,
                                                 const float* __restrict__ Wfc,
                                                 const float* __restrict__ bfc,
                                                 float* __restrict__ out,
                                                 u16* __restrict__ hstate,
                                                 float* __restrict__ poolws,
                                                 int tlen, int first, int last) {
  extern __shared__ __align__(16) char lds[];
  char* hbuf = lds;                            // 16 KB
  char* sb0  = lds + 16384;                    // 64 KB
  char* sb1  = lds + 16384 + 65536;            // 64 KB

  const int tid = threadIdx.x, w = tid >> 6, l = tid & 63;
  const int g = blockIdx.x;                    // batch rows g*16 .. g*16+15
  const int lr = l & 15, k8 = l >> 4;

  // ---- h init: zeros (first chunk) or reload carried state ----
  if (first) {
    f32x4 z = {0.f, 0.f, 0.f, 0.f};
    *(f32x4*)(hbuf + tid * 32) = z;
    *(f32x4*)(hbuf + tid * 32 + 16) = z;
  } else {
    int rr = tid >> 5, c0 = (tid & 31) * 16;
    const u16* src = hstate + (size_t)(g * 16 + rr) * 512 + c0;
#pragma unroll
    for (int j = 0; j < 16; j++) {
      int c = c0 + j;
      *(u16*)(hbuf + rr * 1024 + (((c >> 3) ^ (rr & 7)) << 4) + (c & 7) * 2) = src[j];
    }
  }

  auto stagePair = [&](char* dst, int kt) {    // stage tiles kt, kt+1 (64KB)
    const char* src = (const char*)whhT;
#pragma unroll
    for (int t2 = 0; t2 < 2; t2++) {
      size_t tb = (size_t)(kt + t2) * 32768;
#pragma unroll
      for (int r = 0; r < 4; r++) {
        int off = r * 8192 + w * 1024;
        glds16(src + tb + off + l * 16, dst + t2 * 32768 + off);
      }
    }
  };
  auto readB = [&](const char* tile, int ct) -> short8 {
    int n = w * 64 + ct * 16 + lr;
    return *(const short8*)(tile + n * 64 + ((k8 ^ ((n >> 2) & 3)) << 4));
  };
  auto readA = [&](int kt) -> short8 {         // h fragment, rows 0..15
    int slot = kt * 4 + k8;                    // 6-bit slot
    return *(const short8*)(hbuf + lr * 1024 + ((slot ^ (lr & 7)) << 4));
  };

  // ---- resident B fragments for K-tiles 0..BRES-1 ----
  short8 Breg[BRES][4];
#pragma unroll
  for (int kp = 0; kp < BRES; kp += 2) {
    __syncthreads();
    stagePair(sb0, kp);
    __syncthreads();
#pragma unroll
    for (int t2 = 0; t2 < 2; t2++)
#pragma unroll
      for (int ct = 0; ct < 4; ct++)
        Breg[kp + t2][ct] = readB(sb0 + t2 * 32768, ct);
  }

  float pool[4][4];
  if (first) {
#pragma unroll
    for (int ct = 0; ct < 4; ct++)
#pragma unroll
      for (int i = 0; i < 4; i++) pool[ct][i] = 0.f;
  } else {
#pragma unroll
    for (int ct = 0; ct < 4; ct++)
#pragma unroll
      for (int i = 0; i < 4; i++)
        pool[ct][i] = poolws[(size_t)(g * 16 + k8 * 4 + i) * 512 + w * 64 + ct * 16 + lr];
  }
  __syncthreads();                             // h + sb0 settled

  for (int t = 0; t < tlen; t++) {
    stagePair(sb0, BRES);                      // tiles 10,11 under compute
    const u16* prow = P + (size_t)(t * 256 + g * 16) * 512;
    u16 pv[4][4];
#pragma unroll
    for (int ct = 0; ct < 4; ct++)
#pragma unroll
      for (int i = 0; i < 4; i++)
        pv[ct][i] = prow[(k8 * 4 + i) * 512 + w * 64 + ct * 16 + lr];

    f32x4 acc[4];
    { f32x4 z = {0.f, 0.f, 0.f, 0.f};
#pragma unroll
      for (int ct = 0; ct < 4; ct++) acc[ct] = z; }

    auto streamPhase = [&](const char* buf, int ktbase) {
#pragma unroll
      for (int t2 = 0; t2 < 2; t2++) {
        short8 a = readA(ktbase + t2);
#pragma unroll
        for (int ct = 0; ct < 4; ct++)
          acc[ct] = __builtin_amdgcn_mfma_f32_16x16x32_bf16(a, readB(buf + t2 * 32768, ct), acc[ct], 0, 0, 0);
      }
    };

#pragma unroll
    for (int kt = 0; kt < BRES; kt++) {        // resident part
      short8 a = readA(kt);
#pragma unroll
      for (int ct = 0; ct < 4; ct++)
        acc[ct] = __builtin_amdgcn_mfma_f32_16x16x32_bf16(a, Breg[kt][ct], acc[ct], 0, 0, 0);
    }
    __syncthreads();                           // pair{10,11} landed
    stagePair(sb1, BRES + 2);                  // 12,13
    streamPhase(sb0, BRES);
    __syncthreads();                           // pair{12,13} landed, sb0 free
    stagePair(sb0, BRES + 4);                  // 14,15
    streamPhase(sb1, BRES + 2);
    __syncthreads();                           // pair{14,15} landed, sb1 free
    streamPhase(sb0, BRES + 4);
    __syncthreads();                           // ALL h reads done -> writable

    // h' = relu(P_t + h@Whh); pool += h'; write h' in place
#pragma unroll
    for (int ct = 0; ct < 4; ct++)
#pragma unroll
      for (int i = 0; i < 4; i++) {
        float v = acc[ct][i] + bf2f(pv[ct][i]);
        v = fmaxf(v, 0.f);
        pool[ct][i] += v;
        int rr = k8 * 4 + i;
        int c  = w * 64 + ct * 16 + lr;
        *(u16*)(hbuf + rr * 1024 + (((c >> 3) ^ (rr & 7)) << 4) + (c & 7) * 2) = f2bf(v);
      }
    __syncthreads();                           // h' visible for next step
  }

  if (!last) {                                 // carry state to next chunk
#pragma unroll
    for (int ct = 0; ct < 4; ct++)
#pragma unroll
      for (int i = 0; i < 4; i++)
        poolws[(size_t)(g * 16 + k8 * 4 + i) * 512 + w * 64 + ct * 16 + lr] = pool[ct][i];
    int rr = tid >> 5, c0 = (tid & 31) * 16;
    u16* dst = hstate + (size_t)(g * 16 + rr) * 512 + c0;
#pragma unroll
    for (int j = 0; j < 16; j++) {
      int c = c0 + j;
      dst[j] = *(const u16*)(hbuf + rr * 1024 + (((c >> 3) ^ (rr & 7)) << 4) + (c & 7) * 2);
    }
    return;
  }

  // ---- last chunk: fused mean-pool + FC ----
  float* pl = (float*)sb0;                     // [16][512] f32
#pragma unroll
  for (int ct = 0; ct < 4; ct++)
#pragma unroll
    for (int i = 0; i < 4; i++)
      pl[(k8 * 4 + i) * 512 + w * 64 + ct * 16 + lr] = pool[ct][i] * (1.0f / 200.0f);
  __syncthreads();

  const int rr = l >> 2, oo = l & 3;           // 16 rows x 4 outs per wave
  float s = 0.f;
  for (int kk = 0; kk < 64; kk++) {
    int k = w * 64 + kk;
    s += pl[rr * 512 + k] * Wfc[k * 4 + oo];
  }
  float* part = (float*)sb1;
  part[(w * 16 + rr) * 4 + oo] = s;
  __syncthreads();
  if (w == 0) {
    float v = bfc[oo];
#pragma unroll
    for (int p = 0; p < 8; p++) v += part[(p * 16 + rr) * 4 + oo];
    out[(g * 16 + rr) * 4 + oo] = v;
  }
}

// ---------------------------------------------------------------------------
extern "C" void kernel_launch(void* const* d_in, const int* in_sizes, int n_in,
                              void* d_out, int out_size, void* d_ws, size_t ws_size,
                              hipStream_t stream) {
  (void)in_sizes; (void)n_in; (void)out_size;
  const int*   x   = (const int*)  d_in[0];
  const float* emb = (const float*)d_in[1];
  const float* Wxh = (const float*)d_in[2];
  const float* bxh = (const float*)d_in[3];
  const float* Whh = (const float*)d_in[4];
  const float* bhh = (const float*)d_in[5];
  const float* Wfc = (const float*)d_in[6];
  const float* bfc = (const float*)d_in[7];
  float* out = (float*)d_out;

  u16*   wxhT   = (u16*)d_ws;                            // 512 KB
  u16*   whhT   = (u16*)((char*)d_ws + (512 << 10));     // 512 KB
  u16*   hstate = (u16*)((char*)d_ws + (1024 << 10));    // 256 KB
  float* poolws = (float*)((char*)d_ws + (1280 << 10));  // 512 KB
  u16*   P      = (u16*)((char*)d_ws + (2048 << 10));    // tc * 256 KB

  // largest divisor of 200 (capped at 50 for L2-hot P) that fits ws
  const int divs[10] = {50, 40, 25, 20, 10, 8, 5, 4, 2, 1};
  int tc = 1;
  for (int i = 0; i < 10; i++) {
    size_t need = (size_t)(2 << 20) + (size_t)divs[i] * 262144;
    if (need <= ws_size) { tc = divs[i]; break; }
  }
  int nch = 200 / tc;

  hipFuncSetAttribute((const void*)k2_rnn,
                      hipFuncAttributeMaxDynamicSharedMemorySize, K2_LDS);

  k0_pack<<<256, 256, 0, stream>>>(Wxh, Whh, wxhT, whhT);
  for (int c = 0; c < nch; c++) {
    dim3 g1(2 * tc, 4);
    k1_proj<<<g1, 256, 0, stream>>>(x, emb, wxhT, bxh, bhh, P, c * tc);
    k2_rnn<<<16, 512, K2_LDS, stream>>>(whhT, P, Wfc, bfc, out, hstate, poolws,
                                        tc, (c == 0) ? 1 : 0, (c == nch - 1) ? 1 : 0);
  }
}